// Round 7
// baseline (158.393 us; speedup 1.0000x reference)
//
#include <hip/hip_runtime.h>
#include <math.h>

#define SEQ   1024
#define DQ    256
#define DVD   512
#define NHH   16          // B*NH
#define EPSF  1e-6f
#define INV_SQRT_D 0.0625f   // 1/sqrt(256)

typedef __attribute__((ext_vector_type(8)))  short short8v;
typedef __attribute__((ext_vector_type(16))) float f32x16;

// ---- workspace layout (float offsets) ----
#define WS_FG    0                        // [16][1024]
#define WS_IG    (NHH*SEQ)                // [16][1024]
#define WS_ELIM  (2*NHH*SEQ)              // [16][1024]  exp(-m_t)
#define WS_HDEN  (3*NHH*SEQ)              // [16][1024]
#define WS_AT    (4*NHH*SEQ)              // [16][1024]  a_t = F_t - m_t
#define WS_CS    (5*NHH*SEQ)              // [16][1024]  c_s = i_s - F_s
#define WS_UT    (6*NHH*SEQ)              // [16][1024]  u_t (final C/n weight)
#define WS_AC    (7*NHH*SEQ)              // [16][16]
#define WS_BVEC  (WS_AC + NHH*16)         // [16][16][256]
#define WS_NST   (WS_BVEC + NHH*16*DQ)    // [16][16][256]
#define WS_SMALL_FLOATS (WS_NST + NHH*16*DQ)

#define QBF_OFF  ((size_t)WS_SMALL_FLOATS * 4)             // bytes (16-aligned)
#define KBF_OFF  (QBF_OFF + (size_t)NHH*SEQ*DQ*2)
#define VTB_OFF  (KBF_OFF + (size_t)NHH*SEQ*DQ*2)          // vt_bf [h][v][t]
#define KUT_OFF  (VTB_OFF + (size_t)NHH*DVD*SEQ*2)

__device__ __forceinline__ unsigned short f2bf(float f) {
  unsigned int u = __float_as_uint(f);
  return (unsigned short)((u + 0x7fffu + ((u >> 16) & 1u)) >> 16);
}

__device__ __forceinline__ void gl_lds16(const void* g, void* l) {
  __builtin_amdgcn_global_load_lds(
      (const __attribute__((address_space(1))) unsigned int*)g,
      (__attribute__((address_space(3))) unsigned int*)l, 16, 0, 0);
}

// ============================================================
// Gates: wave-shfl scans. Emits fg, ig, exp(-m), a_t, c_s, u_t, AC, m_out.
// ============================================================
__global__ __launch_bounds__(1024) void gates_kernel(
    const float* __restrict__ ipre, const float* __restrict__ fpre,
    float* __restrict__ ws, float* __restrict__ m_out) {
  const int hh = blockIdx.x;
  const int t  = threadIdx.x;
  const int lane = t & 63, wid = t >> 6;   // 16 waves
  __shared__ float Fs[SEQ];
  __shared__ float Ms[SEQ];
  __shared__ float wsum[16];
  __shared__ float wmax[16];

  const float fp = fpre[hh*SEQ + t];
  const float ip = ipre[hh*SEQ + t];
  const float flog = fminf(fp, 0.f) - log1pf(expf(-fabsf(fp)));

  float v = flog;
  #pragma unroll
  for (int off = 1; off < 64; off <<= 1) {
    float o = __shfl_up(v, off, 64);
    if (lane >= off) v += o;
  }
  if (lane == 63) wsum[wid] = v;
  __syncthreads();
  float woff = 0.f;
  #pragma unroll
  for (int i = 0; i < 16; ++i) { float s = wsum[i]; if (i < wid) woff += s; }
  const float F = v + woff;
  Fs[t] = F;

  float zm = ip - F;
  #pragma unroll
  for (int off = 1; off < 64; off <<= 1) {
    float o = __shfl_up(zm, off, 64);
    if (lane >= off) zm = fmaxf(zm, o);
  }
  if (lane == 63) wmax[wid] = zm;
  __syncthreads();
  float zoff = -INFINITY;
  #pragma unroll
  for (int i = 0; i < 16; ++i) { float s = wmax[i]; if (i < wid) zoff = fmaxf(zoff, s); }
  const float zfull = fmaxf(zm, zoff);
  const float m_t = F + fmaxf(zfull, 0.f);
  Ms[t] = m_t;
  __syncthreads();

  const float m_prev = (t == 0) ? 0.f : Ms[t - 1];
  const float F_end = Fs[SEQ-1], m_end = Ms[SEQ-1];

  ws[WS_FG   + hh*SEQ + t] = expf(flog + m_prev - m_t);
  ws[WS_IG   + hh*SEQ + t] = expf(ip - m_t);
  ws[WS_ELIM + hh*SEQ + t] = expf(-m_t);
  ws[WS_AT   + hh*SEQ + t] = F - m_t;
  ws[WS_CS   + hh*SEQ + t] = ip - F;
  ws[WS_UT   + hh*SEQ + t] = expf(F_end - F + ip - m_end);
  if (t == SEQ - 1) m_out[hh] = m_t;
  if ((t & 63) == 63) {
    const int c = t >> 6;
    const float Fprev  = (c == 0) ? 0.f : Fs[t - 64];
    const float mprevc = (c == 0) ? 0.f : Ms[t - 64];
    ws[WS_AC + hh*16 + c] = expf((F - Fprev) + (mprevc - m_t));
  }
}

// ============================================================
// Role-fused prep kernel (verbatim from passing R5).
//  blocks [0,256): (head,chunk64) — read k ONCE: k_bf cast, bvec scan,
//                  kut = bf16(u_t * k) transposed [d][t].
//  blocks [256,768): (head, 32-row t-group) — v -> vt_bf [h][v][t].
// ============================================================
__global__ __launch_bounds__(256) void prep_kernel(
    const float* __restrict__ kin, const float* __restrict__ vin,
    float* __restrict__ ws,
    unsigned short* __restrict__ k_bf, unsigned short* __restrict__ vt_bf,
    unsigned short* __restrict__ kut) {
  __shared__ float lk[64][257];
  const int b = blockIdx.x;
  if (b < 256) {
    const int hh = b >> 4, c = b & 15;
    const int d = threadIdx.x;
    const int tbase = hh*SEQ + c*64;
    const size_t base = (size_t)tbase * DQ;
    #pragma unroll 4
    for (int tt = 0; tt < 64; ++tt) {
      const float val = kin[base + (size_t)tt*DQ + d];
      lk[tt][d] = val;
      k_bf[base + (size_t)tt*DQ + d] = f2bf(val);
    }
    __syncthreads();
    const float* fg = ws + WS_FG + tbase;
    const float* ig = ws + WS_IG + tbase;
    float nb = 0.f;
    #pragma unroll 8
    for (int tt = 0; tt < 64; ++tt) nb = fg[tt]*nb + ig[tt]*lk[tt][d];
    ws[WS_BVEC + (hh*16 + c)*DQ + d] = nb;
    const float* u = ws + WS_UT + tbase;
    #pragma unroll
    for (int g = 0; g < 8; ++g) {
      short8v pk;
      #pragma unroll
      for (int j = 0; j < 8; ++j) {
        const int tt = g*8 + j;
        pk[j] = (short)f2bf(u[tt] * lk[tt][d]);
      }
      *(short8v*)(kut + ((size_t)(hh*DQ + d))*SEQ + c*64 + g*8) = pk;
    }
  } else {
    const int b2 = b - 256;            // 0..511
    const int hh = b2 >> 5, tg = b2 & 31;
    const int tx = threadIdx.x & 31, ty = threadIdx.x >> 5;
    float (*tile)[33] = (float(*)[33])lk;
    for (int vt = 0; vt < 16; ++vt) {
      #pragma unroll
      for (int i = 0; i < 4; ++i)
        tile[ty + 8*i][tx] =
            vin[((size_t)(hh*SEQ + tg*32 + ty + 8*i))*DVD + vt*32 + tx];
      __syncthreads();
      #pragma unroll
      for (int i = 0; i < 4; ++i)
        vt_bf[((size_t)(hh*DVD + vt*32 + ty + 8*i))*SEQ + tg*32 + tx] =
            f2bf(tile[tx][ty + 8*i]);
      __syncthreads();
    }
  }
}

// ============================================================
// nscan: 16-chunk affine scan of n (exact fp32)
// ============================================================
__global__ __launch_bounds__(256) void nscan_kernel(
    float* __restrict__ ws, float* __restrict__ n_out) {
  const int hh = blockIdx.x;
  const int d  = threadIdx.x;
  float n = 0.f;
  for (int c = 0; c < 16; ++c) {
    ws[WS_NST + (hh*16 + c)*DQ + d] = n;
    n = ws[WS_AC + hh*16 + c]*n + ws[WS_BVEC + (hh*16 + c)*DQ + d];
  }
  n_out[hh*DQ + d] = n;
}

// ============================================================
// hden (exact fp32) + fused q_bf cast (q/16 -> bf16)
// ============================================================
__global__ __launch_bounds__(256) void hden_kernel(
    const float* __restrict__ kin, const float* __restrict__ qin,
    float* __restrict__ ws, unsigned short* __restrict__ q_bf) {
  const int hh = blockIdx.x >> 4;
  const int c  = blockIdx.x & 15;
  const int d  = threadIdx.x;
  __shared__ float pbuf[64][DQ];
  float n = ws[WS_NST + (hh*16 + c)*DQ + d];
  const int tbase = hh*SEQ + c*64;
  const size_t base = (size_t)tbase * DQ;
  #pragma unroll 4
  for (int tt = 0; tt < 64; ++tt) {
    const float fg = ws[WS_FG + tbase + tt];
    const float ig = ws[WS_IG + tbase + tt];
    n = fg*n + ig*kin[base + (size_t)tt*DQ + d];
    const float qv = qin[base + (size_t)tt*DQ + d];
    q_bf[base + (size_t)tt*DQ + d] = f2bf(qv * INV_SQRT_D);
    pbuf[tt][d] = n * qv;
  }
  __syncthreads();
  if (d < 64) {
    float s = 0.f;
    #pragma unroll 8
    for (int jj = 0; jj < DQ; ++jj) s += pbuf[d][(d + jj) & (DQ - 1)];
    const float qn = s * INV_SQRT_D;
    const float hd = fmaxf(fabsf(qn), ws[WS_ELIM + tbase + d]) + EPSF;
    ws[WS_HDEN + tbase + d] = hd;
  }
}

// ============================================================
// Attention main kernel.
// 256 blocks = 8 xcd x {2 heads x 4 pair x 4 vq}. Each block: two 128-row
// q-tiles (qA=7-p long, qB=p short) done SEQUENTIALLY -> uniform 18 chunks.
// 8 waves all-active: role (tsub 0..3, u 0..1): S-phase u=sblk, PV u=vsub.
// K: LDS dbuf 2x32KB, staged 1 chunk ahead (vmcnt(0) at top is free).
// V: streamed to regs from L2-hot vt_bf (8 frags prefetched at S-start).
// P: single 16KB buffer. 2 barriers/chunk. LDS total 80 KB.
// ============================================================
__global__ __launch_bounds__(512, 2) void attn_kernel(
    const unsigned short* __restrict__ q_bf,
    const unsigned short* __restrict__ k_bf,
    const unsigned short* __restrict__ vt_bf,
    const float* __restrict__ ws,
    float* __restrict__ h_out) {
  const int blk = blockIdx.x;
  const int xcd = blk & 7, slot = blk >> 3;
  const int hh  = xcd*2 + (slot & 1);      // 2 heads per XCD
  const int rem = slot >> 1;               // 0..15
  const int p   = rem & 3;                 // pair id
  const int vo  = rem >> 2;                // 0..3: 128-wide v-quarter

  const int tid = threadIdx.x;
  const int w = tid >> 6, lane = tid & 63, l31 = lane & 31, hl = lane >> 5;
  const int tsub = w >> 1;                 // 0..3 (32-t rows of 128)
  const int u    = w & 1;                  // S: sblk / PV: vsub

  __shared__ unsigned short Kb[2][64*256]; // 2 x 32 KB  [s][d-slots]
  __shared__ unsigned short Pb[128*64];    // 16 KB      [t][s]

  const float* c_g  = ws + WS_CS   + hh*SEQ;
  const float* hd_g = ws + WS_HDEN + hh*SEQ;
  const float* a_g  = ws + WS_AT   + hh*SEQ;

  const int qA = 7 - p, qB = p;
  const int nchA = 16 - 2*p;               // chunks for tile A (18 total)

  // V register-stream pointers (fixed per block/lane)
  const unsigned short* vb0p = vt_bf +
      ((size_t)(hh*DVD + vo*128 + u*64 + l31))*SEQ + hl*8;
  const unsigned short* vb1p = vb0p + (size_t)32*SEQ;

  auto stageK = [&](int g) {
    const int j = (g < nchA) ? g : (g - nchA);
    const int s0j = j*64;
    char* dst = (char*)&Kb[g & 1][0];
    #pragma unroll
    for (int p4 = 0; p4 < 4; ++p4) {
      const int uu = p4*512 + tid;
      const int row = uu >> 5, sl = uu & 31;
      const unsigned short* src = k_bf +
          ((size_t)(hh*SEQ + s0j + row))*DQ + ((sl ^ (row & 31))*8);
      gl_lds16(src, dst + (p4*8 + w)*1024);
    }
  };

  // per-tile state
  short8v qfrag[16];
  float a_t = 0.f;
  int tqv = 0;
  auto loadQ = [&](int qt) {
    const int tq2 = qt*128 + tsub*32 + l31;
    tqv = tq2;
    a_t = a_g[tq2];
    const unsigned short* qp = q_bf + ((size_t)(hh*SEQ + tq2))*DQ + hl*8;
    #pragma unroll
    for (int d = 0; d < 16; ++d) qfrag[d] = *(const short8v*)(qp + d*16);
  };

  f32x16 acc0 = {}, acc1 = {};
  auto flushH = [&](int qt) {
    #pragma unroll
    for (int r = 0; r < 16; ++r) {
      const int tl = tsub*32 + (r & 3) + 8*(r >> 2) + 4*hl;
      const int tg = qt*128 + tl;
      const float inv = 1.0f / hd_g[tg];
      const size_t ob = ((size_t)(hh*SEQ + tg))*DVD + vo*128 + u*64 + l31;
      h_out[ob]      = acc0[r] * inv;
      h_out[ob + 32] = acc1[r] * inv;
    }
  };

  loadQ(qA);
  stageK(0);

  const int prow = tsub*32 + l31;          // P row (t) this lane writes/reads
  const int srow = u*32 + l31;             // K row (s) this lane reads (S-phase)

  for (int g = 0; g < 18; ++g) {
    const bool inB = (g >= nchA);
    const int j = inB ? (g - nchA) : g;
    const int s0 = j*64;
    const int buf = g & 1;

    // ---- top barrier: K(g) arrived (issued a full chunk ago) ----
    asm volatile("s_waitcnt vmcnt(0)" ::: "memory");
    __builtin_amdgcn_sched_barrier(0);
    __builtin_amdgcn_s_barrier();
    __builtin_amdgcn_sched_barrier(0);

    if (g == nchA) {                       // tile switch
      flushH(qA);
      #pragma unroll
      for (int r = 0; r < 16; ++r) { acc0[r] = 0.f; acc1[r] = 0.f; }
      loadQ(qB);
    }
    if (g + 1 < 18) stageK(g + 1);         // in flight across both phases

    // ---- V prefetch to regs (consumed in PV after mid barrier) ----
    short8v vf0[4], vf1[4];
    #pragma unroll
    for (int ks = 0; ks < 4; ++ks) {
      vf0[ks] = *(const short8v*)(vb0p + s0 + ks*16);
      vf1[ks] = *(const short8v*)(vb1p + s0 + ks*16);
    }

    // ---- S-phase: S^T[32s x 32t] ----
    f32x16 sacc = {};
    __builtin_amdgcn_s_setprio(1);
    #pragma unroll
    for (int d = 0; d < 16; ++d) {
      const int d2 = d*2 + hl;
      short8v kf = *(const short8v*)&Kb[buf][srow*256 + ((d2 ^ l31)*8)];
      sacc = __builtin_amdgcn_mfma_f32_32x32x16_bf16(kf, qfrag[d], sacc, 0, 0, 0);
    }
    __builtin_amdgcn_s_setprio(0);

    // ---- weight + mask + pack -> Pb (row-XOR swizzled) ----
    #pragma unroll
    for (int i = 0; i < 8; ++i) {
      const int r0 = 2*i;
      const int sl = u*32 + (r0 & 3) + 8*(r0 >> 2) + 4*hl;
      const int sg = s0 + sl;
      const float cc0 = c_g[sg], cc1 = c_g[sg + 1];
      const float p0 = (sg     <= tqv) ? __expf(a_t + cc0)*sacc[r0]   : 0.f;
      const float p1 = (sg + 1 <= tqv) ? __expf(a_t + cc1)*sacc[r0+1] : 0.f;
      unsigned int pk;
      asm volatile("v_cvt_pk_bf16_f32 %0, %1, %2" : "=v"(pk) : "v"(p0), "v"(p1));
      *(unsigned int*)((char*)Pb + prow*128 + ((sl*2) ^ ((prow & 7) << 4))) = pk;
    }

    // ---- mid barrier: P visible (LDS only; K(g+1) stays in flight) ----
    asm volatile("s_waitcnt lgkmcnt(0)" ::: "memory");
    __builtin_amdgcn_sched_barrier(0);
    __builtin_amdgcn_s_barrier();
    __builtin_amdgcn_sched_barrier(0);

    // ---- PV: acc[32t x 64v] += P[32t x 64s] * V[64s x 64v] ----
    __builtin_amdgcn_s_setprio(1);
    #pragma unroll
    for (int ks = 0; ks < 4; ++ks) {
      const int soff = (ks*16 + hl*8) ^ ((prow & 7) << 3);   // shorts
      short8v pa = *(const short8v*)&Pb[prow*64 + soff];
      acc0 = __builtin_amdgcn_mfma_f32_32x32x16_bf16(pa, vf0[ks], acc0, 0, 0, 0);
      acc1 = __builtin_amdgcn_mfma_f32_32x32x16_bf16(pa, vf1[ks], acc1, 0, 0, 0);
    }
    __builtin_amdgcn_s_setprio(0);
    // loop back: next top barrier separates P reads from next P writes
  }

  flushH(qB);
}

// ============================================================
// C GEMM: C[h][d][v] = sum_t kut[h][d][t] * vt[h][v][t]
// ============================================================
__global__ __launch_bounds__(256, 2) void cgemm_kernel(
    const unsigned short* __restrict__ kut,
    const unsigned short* __restrict__ vt,
    float* __restrict__ C_out) {
  const int b = blockIdx.x;       // 16h x 2mt x 8nt
  const int hh = b >> 4;
  const int mt = (b >> 3) & 1;
  const int nt = b & 7;
  const int tid = threadIdx.x;
  const int w = tid >> 6, lane = tid & 63, l31 = lane & 31, hl = lane >> 5;
  const int mr = w >> 1;
  const int nc = w & 1;

  __shared__ unsigned short Alds[128*64];  // 16 KB, [d][t]
  __shared__ unsigned short Blds[64*64];   //  8 KB, [v][t]

  f32x16 acc0 = {}, acc1 = {};
  for (int c = 0; c < 16; ++c) {
    const int t0 = c*64;
    #pragma unroll
    for (int p = 0; p < 4; ++p) {
      int u = p*256 + tid; int row = u >> 3, slot = u & 7;
      const unsigned short* src = kut +
          ((size_t)(hh*DQ + mt*128 + row))*SEQ + t0 + ((slot ^ (row & 7))*8);
      gl_lds16(src, (char*)Alds + (p*4 + w)*1024);
    }
    #pragma unroll
    for (int p = 0; p < 2; ++p) {
      int u = p*256 + tid; int row = u >> 3, slot = u & 7;
      const unsigned short* src = vt +
          ((size_t)(hh*DVD + nt*64 + row))*SEQ + t0 + ((slot ^ (row & 7))*8);
      gl_lds16(src, (char*)Blds + (p*4 + w)*1024);
    }
    __syncthreads();
    #pragma unroll
    for (int ks = 0; ks < 4; ++ks) {
      const int br = nc*32 + l31;
      short8v bf_ = *(const short8v*)&Blds[br*64 + (((ks*2 + hl) ^ (br & 7))*8)];
      const int ar0 = mr*64 + l31, ar1 = ar0 + 32;
      short8v a0 = *(const short8v*)&Alds[ar0*64 + (((ks*2 + hl) ^ (ar0 & 7))*8)];
      short8v a1 = *(const short8v*)&Alds[ar1*64 + (((ks*2 + hl) ^ (ar1 & 7))*8)];
      acc0 = __builtin_amdgcn_mfma_f32_32x32x16_bf16(a0, bf_, acc0, 0, 0, 0);
      acc1 = __builtin_amdgcn_mfma_f32_32x32x16_bf16(a1, bf_, acc1, 0, 0, 0);
    }
    __syncthreads();
  }
  #pragma unroll
  for (int r = 0; r < 16; ++r) {
    const int dl = (r & 3) + 8*(r >> 2) + 4*hl;
    const int d0 = mt*128 + mr*64 + dl;
    const size_t ob = ((size_t)(hh*DQ + d0))*DVD + nt*64 + nc*32 + l31;
    C_out[ob]            = acc0[r];
    C_out[ob + 32*DVD]   = acc1[r];
  }
}

// ============================================================
extern "C" void kernel_launch(void* const* d_in, const int* in_sizes, int n_in,
                              void* d_out, int out_size, void* d_ws, size_t ws_size,
                              hipStream_t stream) {
  const float* q  = (const float*)d_in[0];
  const float* k  = (const float*)d_in[1];
  const float* v  = (const float*)d_in[2];
  const float* ip = (const float*)d_in[3];
  const float* fp = (const float*)d_in[4];

  float* h_out = (float*)d_out;                       // [16][1024][512]
  float* C_out = h_out + (size_t)NHH*SEQ*DVD;         // [16][256][512]
  float* n_out = C_out + (size_t)NHH*DQ*DVD;          // [16][256]
  float* m_out = n_out + NHH*DQ;                      // [16]
  float* ws    = (float*)d_ws;

  unsigned short* q_bf  = (unsigned short*)((char*)d_ws + QBF_OFF);
  unsigned short* k_bf  = (unsigned short*)((char*)d_ws + KBF_OFF);
  unsigned short* vt_bf = (unsigned short*)((char*)d_ws + VTB_OFF);
  unsigned short* kut   = (unsigned short*)((char*)d_ws + KUT_OFF);

  gates_kernel<<<NHH, 1024, 0, stream>>>(ip, fp, ws, m_out);
  prep_kernel<<<768, 256, 0, stream>>>(k, v, ws, k_bf, vt_bf, kut);
  nscan_kernel<<<NHH, 256, 0, stream>>>(ws, n_out);
  hden_kernel<<<NHH*16, 256, 0, stream>>>(k, q, ws, q_bf);
  attn_kernel<<<256, 512, 0, stream>>>(q_bf, k_bf, vt_bf, ws, h_out);
  cgemm_kernel<<<256, 256, 0, stream>>>(kut, vt_bf, C_out);
}